// Round 1
// baseline (162.691 us; speedup 1.0000x reference)
//
#include <hip/hip_runtime.h>
#include <math.h>

#define HIDDEN 1024
#define EMB    256
#define BROWS  4096
#define CAND   128
#define LN_EPS 1e-12f

// ---------------------------------------------------------------------------
// Kernel 1: G = GELU(A @ W^T + b)    A:[4096,1024]  W:[256,1024]  G:[4096,256]
// Tile 64x64, BK=16, 256 threads, grid (64, 4). Both operands are K-contiguous
// (NT gemm) -> coalesced float4 global loads, transposed store into LDS.
// ---------------------------------------------------------------------------
__global__ __launch_bounds__(256) void k_gemm_gelu(
    const float* __restrict__ A,
    const float* __restrict__ W,
    const float* __restrict__ bias,
    float* __restrict__ G)
{
    __shared__ float As[16][64];
    __shared__ float Bs[16][64];
    const int tid = threadIdx.x;
    const int m0  = blockIdx.x * 64;
    const int n0  = blockIdx.y * 64;
    const int ty  = tid >> 4;          // 0..15
    const int tx  = tid & 15;          // 0..15

    const int lr = tid >> 2;           // 0..63: tile row loaded by this thread
    const int lk = (tid & 3) * 4;      // 0,4,8,12: k sub-offset

    float acc[4][4] = {};

    for (int kt = 0; kt < HIDDEN; kt += 16) {
        float4 av = *(const float4*)&A[(size_t)(m0 + lr) * HIDDEN + kt + lk];
        float4 wv = *(const float4*)&W[(size_t)(n0 + lr) * HIDDEN + kt + lk];
        As[lk + 0][lr] = av.x; As[lk + 1][lr] = av.y;
        As[lk + 2][lr] = av.z; As[lk + 3][lr] = av.w;
        Bs[lk + 0][lr] = wv.x; Bs[lk + 1][lr] = wv.y;
        Bs[lk + 2][lr] = wv.z; Bs[lk + 3][lr] = wv.w;
        __syncthreads();
        #pragma unroll
        for (int k = 0; k < 16; ++k) {
            float4 a = *(const float4*)&As[k][ty * 4];
            float4 b = *(const float4*)&Bs[k][tx * 4];
            float ar[4] = {a.x, a.y, a.z, a.w};
            float br[4] = {b.x, b.y, b.z, b.w};
            #pragma unroll
            for (int i = 0; i < 4; ++i)
                #pragma unroll
                for (int j = 0; j < 4; ++j)
                    acc[i][j] = fmaf(ar[i], br[j], acc[i][j]);
        }
        __syncthreads();
    }

    #pragma unroll
    for (int i = 0; i < 4; ++i) {
        float4 o;
        float* op = &o.x;
        #pragma unroll
        for (int j = 0; j < 4; ++j) {
            float v = acc[i][j] + bias[n0 + tx * 4 + j];
            // exact GELU: x * 0.5 * (1 + erf(x / sqrt(2)))
            v = 0.5f * v * (1.0f + erff(v * 0.70710678118654752f));
            op[j] = v;
        }
        *(float4*)&G[(size_t)(m0 + ty * 4 + i) * EMB + n0 + tx * 4] = o;
    }
}

// ---------------------------------------------------------------------------
// Kernel 2: in-place LayerNorm over rows of 256. One wave per row.
// ---------------------------------------------------------------------------
__global__ __launch_bounds__(256) void k_ln(
    float* __restrict__ G,
    const float* __restrict__ gamma,
    const float* __restrict__ beta)
{
    const int tid  = threadIdx.x;
    const int lane = tid & 63;
    const int row  = blockIdx.x * 4 + (tid >> 6);

    float4 v = *(const float4*)&G[(size_t)row * EMB + lane * 4];
    float s = v.x + v.y + v.z + v.w;
    #pragma unroll
    for (int m = 32; m >= 1; m >>= 1) s += __shfl_xor(s, m);
    const float mu = s * (1.0f / 256.0f);

    const float dx = v.x - mu, dy = v.y - mu, dz = v.z - mu, dw = v.w - mu;
    float q = dx * dx + dy * dy + dz * dz + dw * dw;
    #pragma unroll
    for (int m = 32; m >= 1; m >>= 1) q += __shfl_xor(q, m);
    const float scale = 1.0f / sqrtf(q * (1.0f / 256.0f) + LN_EPS);

    float4 g  = *(const float4*)&gamma[lane * 4];
    float4 bb = *(const float4*)&beta[lane * 4];
    float4 o;
    o.x = dx * scale * g.x + bb.x;
    o.y = dy * scale * g.y + bb.y;
    o.z = dz * scale * g.z + bb.z;
    o.w = dw * scale * g.w + bb.w;
    *(float4*)&G[(size_t)row * EMB + lane * 4] = o;
}

// ---------------------------------------------------------------------------
// Kernel 3: scores[b,c] = dot(table[idx[b,c]], H[b]) + ebias[idx[b,c]]
// One block per b (4 waves); wave handles 32 candidates; lane loads float4 of
// the 1KB table row (fully coalesced), 6-step shuffle reduce.
// ---------------------------------------------------------------------------
__global__ __launch_bounds__(256) void k_scores(
    const float* __restrict__ H,
    const float* __restrict__ table,
    const float* __restrict__ ebias,
    const int*   __restrict__ cidx,
    float* __restrict__ out)
{
    __shared__ int sidx[CAND];
    const int b    = blockIdx.x;
    const int tid  = threadIdx.x;
    const int lane = tid & 63;
    const int wave = tid >> 6;

    if (tid < CAND) sidx[tid] = cidx[(size_t)b * CAND + tid];
    const float4 hv = *(const float4*)&H[(size_t)b * EMB + lane * 4];
    __syncthreads();

    #pragma unroll 2
    for (int i = 0; i < 32; ++i) {
        const int c   = wave * 32 + i;
        const int idx = sidx[c];
        const float4 tv = *(const float4*)&table[(size_t)idx * EMB + lane * 4];
        float s = tv.x * hv.x + tv.y * hv.y + tv.z * hv.z + tv.w * hv.w;
        #pragma unroll
        for (int m = 32; m >= 1; m >>= 1) s += __shfl_xor(s, m);
        if (lane == 0) out[(size_t)b * CAND + c] = s + ebias[idx];
    }
}

// ---------------------------------------------------------------------------
extern "C" void kernel_launch(void* const* d_in, const int* in_sizes, int n_in,
                              void* d_out, int out_size, void* d_ws, size_t ws_size,
                              hipStream_t stream) {
    const float* hidden = (const float*)d_in[0];   // [4096,1024]
    const float* Wd     = (const float*)d_in[1];   // [256,1024]
    const float* bd     = (const float*)d_in[2];   // [256]
    const float* gamma  = (const float*)d_in[3];   // [256]
    const float* beta   = (const float*)d_in[4];   // [256]
    const float* table  = (const float*)d_in[5];   // [500000,256]
    const float* ebias  = (const float*)d_in[6];   // [500000]
    const int*   cidx   = (const int*)d_in[7];     // [4096,128]
    float* out = (float*)d_out;                    // [4096,128]

    float* G = (float*)d_ws;                       // 4096*256 f32 = 4 MB scratch

    k_gemm_gelu<<<dim3(BROWS / 64, EMB / 64), 256, 0, stream>>>(hidden, Wd, bd, G);
    k_ln<<<dim3(BROWS / 4), 256, 0, stream>>>(G, gamma, beta);
    k_scores<<<dim3(BROWS), 256, 0, stream>>>(G, table, ebias, cidx, out);
}

// Round 2
// 147.267 us; speedup vs baseline: 1.1047x; 1.1047x over previous
//
#include <hip/hip_runtime.h>
#include <hip/hip_bf16.h>
#include <math.h>

#define HIDDEN 1024
#define EMB    256
#define BROWS  4096
#define CAND   128
#define LN_EPS 1e-12f

typedef __attribute__((ext_vector_type(8))) short bf16x8;   // 8 bf16 in 4 VGPRs
typedef __attribute__((ext_vector_type(4))) float f32x4;

__device__ __forceinline__ int swz(int row, int slot) { return slot ^ ((row >> 1) & 3); }

__device__ __forceinline__ unsigned short f2bf(float f) {
    __bf16 h = (__bf16)f;                       // RN; compiler pairs into v_cvt_pk_bf16_f32
    return __builtin_bit_cast(unsigned short, h);
}

// ---------------------------------------------------------------------------
// Fused: H = LayerNorm(GELU(A @ W^T + b)) * gamma + beta
// A:[4096,1024] f32, W:[256,1024] f32, H:[4096,256] f32
// BM=64, BN=256(full), BK=32; 4 waves, each 64Mx64N (4x4 frags of 16x16x32).
// LN fused in epilogue: 16-lane shfl partials + cross-wave LDS reduce.
// ---------------------------------------------------------------------------
__global__ __launch_bounds__(256) void k_transform(
    const float* __restrict__ A,
    const float* __restrict__ W,
    const float* __restrict__ bias,
    const float* __restrict__ gamma,
    const float* __restrict__ beta,
    float* __restrict__ G)
{
    __shared__ unsigned short As[64 * 32];    // [row][k] bf16, 16B-slot swizzled
    __shared__ unsigned short Ws[256 * 32];
    __shared__ float part[64][8];             // [row][wave*2 + {sum, sumsq}]

    const int tid  = threadIdx.x;
    const int lane = tid & 63;
    const int wv   = tid >> 6;
    const int m0   = blockIdx.x * 64;

    const int lcol = lane & 15;   // frag row/col index
    const int lk   = lane >> 4;   // k-chunk 0..3

    const int arow = tid >> 2;    // A stage: row 0..63
    const int apr  = tid & 3;     // A stage: k-slot 0..3

    f32x4 acc[4][4] = {};

    for (int kt = 0; kt < HIDDEN; kt += 32) {
        // ---- global loads (fp32) ----
        float4 a0 = *(const float4*)&A[(size_t)(m0 + arow) * HIDDEN + kt + apr * 8];
        float4 a1 = *(const float4*)&A[(size_t)(m0 + arow) * HIDDEN + kt + apr * 8 + 4];
        float4 w0[4], w1[4];
        #pragma unroll
        for (int i = 0; i < 4; ++i) {
            int id = tid + i * 256;
            int row = id >> 2, pr = id & 3;
            w0[i] = *(const float4*)&W[(size_t)row * HIDDEN + kt + pr * 8];
            w1[i] = *(const float4*)&W[(size_t)row * HIDDEN + kt + pr * 8 + 4];
        }
        __syncthreads();          // previous iteration's frag reads done
        // ---- convert + LDS store ----
        {
            bf16x8 v;
            v[0]=f2bf(a0.x); v[1]=f2bf(a0.y); v[2]=f2bf(a0.z); v[3]=f2bf(a0.w);
            v[4]=f2bf(a1.x); v[5]=f2bf(a1.y); v[6]=f2bf(a1.z); v[7]=f2bf(a1.w);
            *(bf16x8*)&As[arow * 32 + swz(arow, apr) * 8] = v;
        }
        #pragma unroll
        for (int i = 0; i < 4; ++i) {
            int id = tid + i * 256;
            int row = id >> 2, pr = id & 3;
            bf16x8 v;
            v[0]=f2bf(w0[i].x); v[1]=f2bf(w0[i].y); v[2]=f2bf(w0[i].z); v[3]=f2bf(w0[i].w);
            v[4]=f2bf(w1[i].x); v[5]=f2bf(w1[i].y); v[6]=f2bf(w1[i].z); v[7]=f2bf(w1[i].w);
            *(bf16x8*)&Ws[row * 32 + swz(row, pr) * 8] = v;
        }
        __syncthreads();
        // ---- fragments + MFMA ----
        bf16x8 af[4], bfr[4];
        #pragma unroll
        for (int m = 0; m < 4; ++m) {
            int r = m * 16 + lcol;
            af[m] = *(const bf16x8*)&As[r * 32 + swz(r, lk) * 8];
        }
        #pragma unroll
        for (int n = 0; n < 4; ++n) {
            int r = wv * 64 + n * 16 + lcol;
            bfr[n] = *(const bf16x8*)&Ws[r * 32 + swz(r, lk) * 8];
        }
        #pragma unroll
        for (int m = 0; m < 4; ++m)
            #pragma unroll
            for (int n = 0; n < 4; ++n)
                acc[m][n] = __builtin_amdgcn_mfma_f32_16x16x32_bf16(af[m], bfr[n], acc[m][n], 0, 0, 0);
    }

    // ---- epilogue: bias + exact GELU, per-row (sum, sumsq) partials ----
    float bcol[4], gcol[4], becol[4];
    #pragma unroll
    for (int n = 0; n < 4; ++n) {
        int col = wv * 64 + n * 16 + lcol;
        bcol[n]  = bias[col];
        gcol[n]  = gamma[col];
        becol[n] = beta[col];
    }

    float sv[4][4], qv[4][4];     // [m][reg]
    #pragma unroll
    for (int m = 0; m < 4; ++m) {
        #pragma unroll
        for (int r = 0; r < 4; ++r) { sv[m][r] = 0.0f; qv[m][r] = 0.0f; }
        #pragma unroll
        for (int n = 0; n < 4; ++n) {
            #pragma unroll
            for (int r = 0; r < 4; ++r) {
                float v = acc[m][n][r] + bcol[n];
                v = 0.5f * v * (1.0f + erff(v * 0.70710678118654752f));
                acc[m][n][r] = v;
                sv[m][r] += v;
                qv[m][r] += v * v;
            }
        }
        #pragma unroll
        for (int r = 0; r < 4; ++r) {
            #pragma unroll
            for (int msk = 8; msk >= 1; msk >>= 1) {
                sv[m][r] += __shfl_xor(sv[m][r], msk);
                qv[m][r] += __shfl_xor(qv[m][r], msk);
            }
        }
    }
    if (lcol == 0) {
        #pragma unroll
        for (int m = 0; m < 4; ++m)
            #pragma unroll
            for (int r = 0; r < 4; ++r) {
                int R = m * 16 + lk * 4 + r;
                part[R][wv * 2 + 0] = sv[m][r];
                part[R][wv * 2 + 1] = qv[m][r];
            }
    }
    __syncthreads();

    // ---- finish LN, store ----
    #pragma unroll
    for (int m = 0; m < 4; ++m) {
        #pragma unroll
        for (int r = 0; r < 4; ++r) {
            int R = m * 16 + lk * 4 + r;
            float4 p0 = *(const float4*)&part[R][0];
            float4 p1 = *(const float4*)&part[R][4];
            float s  = p0.x + p0.z + p1.x + p1.z;
            float q  = p0.y + p0.w + p1.y + p1.w;
            float mu = s * (1.0f / 256.0f);
            float var = q * (1.0f / 256.0f) - mu * mu;
            float rs = rsqrtf(var + LN_EPS);
            #pragma unroll
            for (int n = 0; n < 4; ++n) {
                int col = wv * 64 + n * 16 + lcol;
                G[(size_t)(m0 + R) * EMB + col] = (acc[m][n][r] - mu) * rs * gcol[n] + becol[n];
            }
        }
    }
}

// ---------------------------------------------------------------------------
// scores[b,c] = dot(table[idx[b,c]], H[b]) + ebias[idx[b,c]]
// ---------------------------------------------------------------------------
__global__ __launch_bounds__(256) void k_scores(
    const float* __restrict__ H,
    const float* __restrict__ table,
    const float* __restrict__ ebias,
    const int*   __restrict__ cidx,
    float* __restrict__ out)
{
    __shared__ int sidx[CAND];
    const int b    = blockIdx.x;
    const int tid  = threadIdx.x;
    const int lane = tid & 63;
    const int wave = tid >> 6;

    if (tid < CAND) sidx[tid] = cidx[(size_t)b * CAND + tid];
    const float4 hv = *(const float4*)&H[(size_t)b * EMB + lane * 4];
    __syncthreads();

    #pragma unroll 2
    for (int i = 0; i < 32; ++i) {
        const int c   = wave * 32 + i;
        const int idx = sidx[c];
        const float4 tv = *(const float4*)&table[(size_t)idx * EMB + lane * 4];
        float s = tv.x * hv.x + tv.y * hv.y + tv.z * hv.z + tv.w * hv.w;
        #pragma unroll
        for (int m = 32; m >= 1; m >>= 1) s += __shfl_xor(s, m);
        if (lane == 0) out[(size_t)b * CAND + c] = s + ebias[idx];
    }
}

// ---------------------------------------------------------------------------
extern "C" void kernel_launch(void* const* d_in, const int* in_sizes, int n_in,
                              void* d_out, int out_size, void* d_ws, size_t ws_size,
                              hipStream_t stream) {
    const float* hidden = (const float*)d_in[0];
    const float* Wd     = (const float*)d_in[1];
    const float* bd     = (const float*)d_in[2];
    const float* gamma  = (const float*)d_in[3];
    const float* beta   = (const float*)d_in[4];
    const float* table  = (const float*)d_in[5];
    const float* ebias  = (const float*)d_in[6];
    const int*   cidx   = (const int*)d_in[7];
    float* out = (float*)d_out;

    float* G = (float*)d_ws;   // 4096*256 f32 = 4 MB

    k_transform<<<dim3(BROWS / 64), 256, 0, stream>>>(hidden, Wd, bd, gamma, beta, G);
    k_scores<<<dim3(BROWS), 256, 0, stream>>>(G, table, ebias, cidx, out);
}

// Round 3
// 135.640 us; speedup vs baseline: 1.1994x; 1.0857x over previous
//
#include <hip/hip_runtime.h>
#include <hip/hip_bf16.h>
#include <math.h>

#define HIDDEN 1024
#define EMB    256
#define BROWS  4096
#define CAND   128
#define LN_EPS 1e-12f

typedef __attribute__((ext_vector_type(8))) short bf16x8;   // 8 bf16 in 4 VGPRs
typedef __attribute__((ext_vector_type(4))) float f32x4;

__device__ __forceinline__ int swz(int row, int slot) { return slot ^ ((row >> 1) & 3); }

__device__ __forceinline__ unsigned short f2bf(float f) {
    __bf16 h = (__bf16)f;                       // RN; pairs into v_cvt_pk_bf16_f32
    return __builtin_bit_cast(unsigned short, h);
}

// ---------------------------------------------------------------------------
// Fused: H = LayerNorm(GELU(A @ W^T + b)) * gamma + beta
// BM=16, BN=256(full row -> LN fused), BK=32; grid=256 (1 block/CU).
// 4 waves, each 16Mx64N (1x4 frags of 16x16x32 bf16 MFMA, fp32 accum).
// ---------------------------------------------------------------------------
__global__ __launch_bounds__(256) void k_transform(
    const float* __restrict__ A,
    const float* __restrict__ W,
    const float* __restrict__ bias,
    const float* __restrict__ gamma,
    const float* __restrict__ beta,
    float* __restrict__ G)
{
    __shared__ unsigned short As[16 * 32];    // [row][k] bf16, 16B-slot swizzled
    __shared__ unsigned short Ws[256 * 32];
    __shared__ float part[16][8];             // [row][wave*2 + {sum, sumsq}]

    const int tid  = threadIdx.x;
    const int lane = tid & 63;
    const int wv   = tid >> 6;
    const int m0   = blockIdx.x * 16;

    const int lcol = lane & 15;   // frag row/col index
    const int lk   = lane >> 4;   // k-chunk 0..3

    f32x4 acc[4] = {};

    for (int kt = 0; kt < HIDDEN; kt += 32) {
        // ---- global loads (fp32) ----
        float4 a0, a1;
        const int arow = tid >> 2, apr = tid & 3;
        if (tid < 64) {
            a0 = *(const float4*)&A[(size_t)(m0 + arow) * HIDDEN + kt + apr * 8];
            a1 = *(const float4*)&A[(size_t)(m0 + arow) * HIDDEN + kt + apr * 8 + 4];
        }
        float4 w0[4], w1[4];
        #pragma unroll
        for (int i = 0; i < 4; ++i) {
            int id = tid + i * 256;
            int row = id >> 2, pr = id & 3;
            w0[i] = *(const float4*)&W[(size_t)row * HIDDEN + kt + pr * 8];
            w1[i] = *(const float4*)&W[(size_t)row * HIDDEN + kt + pr * 8 + 4];
        }
        __syncthreads();          // previous iteration's frag reads done
        // ---- convert + LDS store ----
        if (tid < 64) {
            bf16x8 v;
            v[0]=f2bf(a0.x); v[1]=f2bf(a0.y); v[2]=f2bf(a0.z); v[3]=f2bf(a0.w);
            v[4]=f2bf(a1.x); v[5]=f2bf(a1.y); v[6]=f2bf(a1.z); v[7]=f2bf(a1.w);
            *(bf16x8*)&As[arow * 32 + swz(arow, apr) * 8] = v;
        }
        #pragma unroll
        for (int i = 0; i < 4; ++i) {
            int id = tid + i * 256;
            int row = id >> 2, pr = id & 3;
            bf16x8 v;
            v[0]=f2bf(w0[i].x); v[1]=f2bf(w0[i].y); v[2]=f2bf(w0[i].z); v[3]=f2bf(w0[i].w);
            v[4]=f2bf(w1[i].x); v[5]=f2bf(w1[i].y); v[6]=f2bf(w1[i].z); v[7]=f2bf(w1[i].w);
            *(bf16x8*)&Ws[row * 32 + swz(row, pr) * 8] = v;
        }
        __syncthreads();
        // ---- fragments + MFMA ----
        bf16x8 af = *(const bf16x8*)&As[lcol * 32 + swz(lcol, lk) * 8];
        bf16x8 bfr[4];
        #pragma unroll
        for (int n = 0; n < 4; ++n) {
            int r = wv * 64 + n * 16 + lcol;
            bfr[n] = *(const bf16x8*)&Ws[r * 32 + swz(r, lk) * 8];
        }
        #pragma unroll
        for (int n = 0; n < 4; ++n)
            acc[n] = __builtin_amdgcn_mfma_f32_16x16x32_bf16(af, bfr[n], acc[n], 0, 0, 0);
    }

    // ---- epilogue: bias + exact GELU, per-row (sum, sumsq) partials ----
    float bcol[4], gcol[4], becol[4];
    #pragma unroll
    for (int n = 0; n < 4; ++n) {
        int col = wv * 64 + n * 16 + lcol;
        bcol[n]  = bias[col];
        gcol[n]  = gamma[col];
        becol[n] = beta[col];
    }

    float sv[4] = {}, qv[4] = {};
    #pragma unroll
    for (int n = 0; n < 4; ++n) {
        #pragma unroll
        for (int r = 0; r < 4; ++r) {
            float v = acc[n][r] + bcol[n];
            v = 0.5f * v * (1.0f + erff(v * 0.70710678118654752f));
            acc[n][r] = v;
            sv[r] += v;
            qv[r] += v * v;
        }
    }
    #pragma unroll
    for (int r = 0; r < 4; ++r) {
        #pragma unroll
        for (int msk = 8; msk >= 1; msk >>= 1) {
            sv[r] += __shfl_xor(sv[r], msk);
            qv[r] += __shfl_xor(qv[r], msk);
        }
    }
    if (lcol == 0) {
        #pragma unroll
        for (int r = 0; r < 4; ++r) {
            int R = lk * 4 + r;
            part[R][wv * 2 + 0] = sv[r];
            part[R][wv * 2 + 1] = qv[r];
        }
    }
    __syncthreads();

    #pragma unroll
    for (int r = 0; r < 4; ++r) {
        int R = lk * 4 + r;
        float4 p0 = *(const float4*)&part[R][0];
        float4 p1 = *(const float4*)&part[R][4];
        float s  = p0.x + p0.z + p1.x + p1.z;
        float q  = p0.y + p0.w + p1.y + p1.w;
        float mu = s * (1.0f / 256.0f);
        float var = q * (1.0f / 256.0f) - mu * mu;
        float rs = rsqrtf(var + LN_EPS);
        #pragma unroll
        for (int n = 0; n < 4; ++n) {
            int col = wv * 64 + n * 16 + lcol;
            G[(size_t)(m0 + R) * EMB + col] = (acc[n][r] - mu) * rs * gcol[n] + becol[n];
        }
    }
}

// ---------------------------------------------------------------------------
// scores[b,c] = dot(table[idx[b,c]], H[b]) + ebias[idx[b,c]]
// One block per b. 16 lanes per candidate: lane = q*16+l; wave does 4
// candidates per macro-iter (8 iters, fully unrolled for MLP). Reduction is
// 4 shuffle steps, parallel across the 4 lane groups. No LDS, no barriers.
// ---------------------------------------------------------------------------
__global__ __launch_bounds__(256) void k_scores(
    const float* __restrict__ H,
    const float* __restrict__ table,
    const float* __restrict__ ebias,
    const int*   __restrict__ cidx,
    float* __restrict__ out)
{
    const int b    = blockIdx.x;
    const int tid  = threadIdx.x;
    const int lane = tid & 63;
    const int wv   = tid >> 6;
    const int l    = lane & 15;   // lane within candidate group
    const int q    = lane >> 4;   // candidate within quad

    const float4* Hrow = (const float4*)(H + (size_t)b * EMB);
    float4 hv[4];
    #pragma unroll
    for (int p = 0; p < 4; ++p) hv[p] = Hrow[p * 16 + l];

    const int cbase = wv * 32 + q;
    int idxs[8];
    #pragma unroll
    for (int it = 0; it < 8; ++it)
        idxs[it] = cidx[(size_t)b * CAND + cbase + it * 4];

    #pragma unroll
    for (int it = 0; it < 8; ++it) {
        const float4* row = (const float4*)(table + (size_t)idxs[it] * EMB);
        float4 t0 = row[ 0 + l];
        float4 t1 = row[16 + l];
        float4 t2 = row[32 + l];
        float4 t3 = row[48 + l];
        float  eb = ebias[idxs[it]];
        float s = t0.x*hv[0].x + t0.y*hv[0].y + t0.z*hv[0].z + t0.w*hv[0].w
                + t1.x*hv[1].x + t1.y*hv[1].y + t1.z*hv[1].z + t1.w*hv[1].w
                + t2.x*hv[2].x + t2.y*hv[2].y + t2.z*hv[2].z + t2.w*hv[2].w
                + t3.x*hv[3].x + t3.y*hv[3].y + t3.z*hv[3].z + t3.w*hv[3].w;
        #pragma unroll
        for (int m = 8; m >= 1; m >>= 1) s += __shfl_xor(s, m);
        if (l == 0) out[(size_t)b * CAND + cbase + it * 4] = s + eb;
    }
}

// ---------------------------------------------------------------------------
extern "C" void kernel_launch(void* const* d_in, const int* in_sizes, int n_in,
                              void* d_out, int out_size, void* d_ws, size_t ws_size,
                              hipStream_t stream) {
    const float* hidden = (const float*)d_in[0];
    const float* Wd     = (const float*)d_in[1];
    const float* bd     = (const float*)d_in[2];
    const float* gamma  = (const float*)d_in[3];
    const float* beta   = (const float*)d_in[4];
    const float* table  = (const float*)d_in[5];
    const float* ebias  = (const float*)d_in[6];
    const int*   cidx   = (const int*)d_in[7];
    float* out = (float*)d_out;

    float* G = (float*)d_ws;   // 4096*256 f32 = 4 MB

    k_transform<<<dim3(BROWS / 16), 256, 0, stream>>>(hidden, Wd, bd, gamma, beta, G);
    k_scores<<<dim3(BROWS), 256, 0, stream>>>(G, table, ebias, cidx, out);
}